// Round 1
// baseline (162.546 us; speedup 1.0000x reference)
//
#include <hip/hip_runtime.h>
#include <math.h>

#define N_DIM 64      // feature dim (K)
#define TILE  128     // output tile edge per block
#define LDSP  132     // padded LDS stride: 132%4==0 (float4-aligned), 132%32==4 (2-way banks on reads)

// Matern 5/2 cross-covariance:
//   d2 = max(||a||^2 + ||b||^2 - 2 a.b, 0);  r = sqrt(d2)
//   out = c^2 * (1 + sqrt5*r + 5/3*r^2) * exp(-sqrt5*r)
//
// Block: 256 threads = 4 waves, computes a 128x128 output tile.
// LDS tiles stored K-major (As[d][i]) so the inner product loop does
// float4 reads along the tile-row axis. K=64 fits entirely, no K loop/dbuf.
__global__ __launch_bounds__(256, 2)
void matern52_tile_kernel(const float* __restrict__ X1,
                          const float* __restrict__ X2,
                          const float* __restrict__ cc,
                          const float* __restrict__ l,
                          float* __restrict__ out,
                          int N1, int N2)
{
    __shared__ float As[N_DIM][LDSP];   // X1_l tile, K-major
    __shared__ float Bs[N_DIM][LDSP];   // X2_l tile, K-major
    __shared__ float sqA[TILE];
    __shared__ float sqB[TILE];

    const int t  = threadIdx.x;
    const int bi = blockIdx.y;          // row tile index (X1)
    const int bj = blockIdx.x;          // col tile index (X2)
    const int c4 = t & 15;              // which float4 chunk of the 64-dim row
    const int r0 = t >> 4;              // base row 0..15
    const int d0 = c4 * 4;

    // Per-thread reciprocal lengthscales for its 4 dims (X*(1/l): double
    // rounding vs ref's X/l is ~2^-23 relative -- far below the d2 budget).
    float4 lv  = *reinterpret_cast<const float4*>(&l[d0]);
    const float rl0 = 1.0f / lv.x, rl1 = 1.0f / lv.y,
                rl2 = 1.0f / lv.z, rl3 = 1.0f / lv.w;

    const float* __restrict__ x1base = X1 + (size_t)(bi * TILE) * N_DIM;
    const float* __restrict__ x2base = X2 + (size_t)(bj * TILE) * N_DIM;

    // Stage both tiles (coalesced float4 global reads; transposed scalar LDS
    // writes -- 8-way bank conflict but one-time, <5% of block cycles).
    #pragma unroll
    for (int k = 0; k < 8; ++k) {
        const int row = r0 + 16 * k;
        float4 v1 = *reinterpret_cast<const float4*>(&x1base[row * N_DIM + d0]);
        float4 v2 = *reinterpret_cast<const float4*>(&x2base[row * N_DIM + d0]);
        As[d0 + 0][row] = v1.x * rl0;
        As[d0 + 1][row] = v1.y * rl1;
        As[d0 + 2][row] = v1.z * rl2;
        As[d0 + 3][row] = v1.w * rl3;
        Bs[d0 + 0][row] = v2.x * rl0;
        Bs[d0 + 1][row] = v2.y * rl1;
        Bs[d0 + 2][row] = v2.z * rl2;
        Bs[d0 + 3][row] = v2.w * rl3;
    }
    __syncthreads();

    // Row squared-norms: threads 0..127 -> sqA, 128..255 -> sqB.
    // Lane i reads column i at stride LDSP -> banks distinct mod 32.
    {
        const int i = t & 127;
        const float (*T)[LDSP] = (t < 128) ? As : Bs;
        float s = 0.0f;
        #pragma unroll
        for (int d = 0; d < N_DIM; ++d) {
            const float v = T[d][i];
            s = fmaf(v, v, s);
        }
        if (t < 128) sqA[i] = s; else sqB[i] = s;
    }
    // sq results are only read after the post-loop barrier below.

    const int ty = t >> 4;      // 0..15
    const int tx = t & 15;      // 0..15
    const int ia = ty * 4;      // thread's A-rows: ia..ia+3 and ia+64..ia+67
    const int jb = tx * 4;      // thread's B-rows: jb..jb+3 and jb+64..jb+67

    float acc[8][8];
    #pragma unroll
    for (int m = 0; m < 8; ++m)
        #pragma unroll
        for (int n = 0; n < 8; ++n) acc[m][n] = 0.0f;

    // Hot loop: per d, 4x ds_read_b128 + 64 FMA (16:1 FMA:LDS-instr).
    #pragma unroll 4
    for (int d = 0; d < N_DIM; ++d) {
        float4 a0 = *reinterpret_cast<const float4*>(&As[d][ia]);
        float4 a1 = *reinterpret_cast<const float4*>(&As[d][ia + 64]);
        float4 b0 = *reinterpret_cast<const float4*>(&Bs[d][jb]);
        float4 b1 = *reinterpret_cast<const float4*>(&Bs[d][jb + 64]);
        const float av[8] = {a0.x, a0.y, a0.z, a0.w, a1.x, a1.y, a1.z, a1.w};
        const float bv[8] = {b0.x, b0.y, b0.z, b0.w, b1.x, b1.y, b1.z, b1.w};
        #pragma unroll
        for (int m = 0; m < 8; ++m)
            #pragma unroll
            for (int n = 0; n < 8; ++n)
                acc[m][n] = fmaf(av[m], bv[n], acc[m][n]);
    }

    __syncthreads();   // make sqA/sqB visible

    const float c0 = cc[0];
    const float c2 = c0 * c0;
    const float SQ5   = 2.23606797749978969641f;
    const float FIVE3 = 1.66666666666666666667f;

    float sa[8], sb[8];
    #pragma unroll
    for (int m = 0; m < 4; ++m) { sa[m] = sqA[ia + m]; sa[m + 4] = sqA[ia + 64 + m]; }
    #pragma unroll
    for (int n = 0; n < 4; ++n) { sb[n] = sqB[jb + n]; sb[n + 4] = sqB[jb + 64 + n]; }

    const size_t obase = (size_t)(bi * TILE) * (size_t)N2 + (size_t)(bj * TILE);
    #pragma unroll
    for (int m = 0; m < 8; ++m) {
        const int row = (m < 4) ? (ia + m) : (ia + 60 + m);  // m>=4 -> ia+64+(m-4)
        #pragma unroll
        for (int half = 0; half < 2; ++half) {
            float res[4];
            #pragma unroll
            for (int q = 0; q < 4; ++q) {
                const int n = half * 4 + q;
                float d2 = fmaxf(sa[m] + sb[n] - 2.0f * acc[m][n], 0.0f);
                float r  = sqrtf(d2);
                float e  = __expf(-SQ5 * r);
                res[q] = c2 * fmaf(FIVE3, r * r, fmaf(SQ5, r, 1.0f)) * e;
            }
            const int col = (half == 0) ? jb : (jb + 64);
            *reinterpret_cast<float4*>(&out[obase + (size_t)row * N2 + col]) =
                make_float4(res[0], res[1], res[2], res[3]);
        }
    }
}

extern "C" void kernel_launch(void* const* d_in, const int* in_sizes, int n_in,
                              void* d_out, int out_size, void* d_ws, size_t ws_size,
                              hipStream_t stream) {
    const float* X1 = (const float*)d_in[0];
    const float* X2 = (const float*)d_in[1];
    const float* c  = (const float*)d_in[2];
    const float* l  = (const float*)d_in[3];
    float* out = (float*)d_out;

    const int N1 = in_sizes[0] / N_DIM;   // 8192
    const int N2 = in_sizes[1] / N_DIM;   // 8192

    dim3 grid(N2 / TILE, N1 / TILE);      // 64 x 64 blocks
    matern52_tile_kernel<<<grid, 256, 0, stream>>>(X1, X2, c, l, out, N1, N2);
}

// Round 2
// 113.392 us; speedup vs baseline: 1.4335x; 1.4335x over previous
//
#include <hip/hip_runtime.h>
#include <math.h>

#define N_DIM 64
#define TILE  128

typedef unsigned short ushort_t;
typedef unsigned int   uint_t;
typedef short s16x8 __attribute__((ext_vector_type(8)));
typedef float f32x4 __attribute__((ext_vector_type(4)));

__device__ __forceinline__ ushort_t f2bf(float f) {          // round-to-nearest-even bf16
    uint_t u = __float_as_uint(f);
    u += 0x7FFFu + ((u >> 16) & 1u);
    return (ushort_t)(u >> 16);
}
__device__ __forceinline__ float bf2f(ushort_t h) {
    return __uint_as_float(((uint_t)h) << 16);
}

// Byte offset of 16B chunk kc (0..7) in row `row` of a [128][64] bf16 tile.
// XOR swizzle: without it, 16 lanes reading consecutive rows at one kc hit a
// single 128B-periodic bank column (32-way conflict, G4); XOR spreads 8 rows
// across 8 distinct 16B slots -> 2-way (free).
__device__ __forceinline__ int swz16(int row, int kc) {
    return (row << 7) + ((kc << 4) ^ ((row & 7) << 4));
}

// Matern 5/2 via split-bf16 MFMA:
//   x = hi + lo (bf16 each);  cross = hi.hi + hi.lo + lo.hi  (lo.lo ~ 2^-18 dropped)
//   d2 = max(sqA + sqB - 2*cross, 0);  out = c^2 (1 + s5 r + 5/3 d2) exp(-s5 r)
// Block: 256 thr = 4 waves (2x2), 128x128 output tile. K=64 staged whole.
__global__ __launch_bounds__(256, 2)
void matern52_mfma_kernel(const float* __restrict__ X1,
                          const float* __restrict__ X2,
                          const float* __restrict__ cc,
                          const float* __restrict__ l,
                          float* __restrict__ out,
                          int N1, int N2)
{
    __shared__ ushort_t Ah[TILE * N_DIM], Al[TILE * N_DIM];
    __shared__ ushort_t Bh[TILE * N_DIM], Bl[TILE * N_DIM];
    __shared__ float sqA[TILE], sqB[TILE];

    const int t  = threadIdx.x;
    const int bi = blockIdx.y, bj = blockIdx.x;

    const int kq   = t & 15;   // float4 index within a 64-dim row
    const int rsub = t >> 4;   // row sub-index 0..15

    // reciprocal lengthscales for this thread's 4 dims (x*(1/l): ~2^-23 rel vs ref's x/l)
    float4 lv = *reinterpret_cast<const float4*>(&l[kq * 4]);
    const float rlx = 1.f / lv.x, rly = 1.f / lv.y, rlz = 1.f / lv.z, rlw = 1.f / lv.w;

    const float* x1b = X1 + (size_t)(bi * TILE) * N_DIM;
    const float* x2b = X2 + (size_t)(bj * TILE) * N_DIM;

    // ---- stage: fp32 -> (hi,lo) bf16 tiles + row norms ------------------
    // Each quarter-wave (16 lanes) owns one row per c-iter: coalesced 1KB/wave
    // global float4 loads; 8B swizzled ds_writes; norm via 16-lane shfl reduce.
    #define STAGE(Xb, Th, Tl, SQ)                                              \
    {                                                                          \
        _Pragma("unroll")                                                      \
        for (int c = 0; c < 8; ++c) {                                          \
            const int row = c * 16 + rsub;                                     \
            float4 x = *reinterpret_cast<const float4*>(&(Xb)[row * N_DIM + kq * 4]); \
            float a0 = x.x * rlx, a1 = x.y * rly, a2 = x.z * rlz, a3 = x.w * rlw; \
            ushort_t h0 = f2bf(a0), h1 = f2bf(a1), h2 = f2bf(a2), h3 = f2bf(a3); \
            ushort_t e0 = f2bf(a0 - bf2f(h0)), e1 = f2bf(a1 - bf2f(h1));       \
            ushort_t e2 = f2bf(a2 - bf2f(h2)), e3 = f2bf(a3 - bf2f(h3));       \
            const int off = (row << 7) + (((kq >> 1) << 4) ^ ((row & 7) << 4)) + ((kq & 1) << 3); \
            uint2 hv, lvv;                                                     \
            hv.x  = (uint_t)h0 | ((uint_t)h1 << 16);                           \
            hv.y  = (uint_t)h2 | ((uint_t)h3 << 16);                           \
            lvv.x = (uint_t)e0 | ((uint_t)e1 << 16);                           \
            lvv.y = (uint_t)e2 | ((uint_t)e3 << 16);                           \
            *reinterpret_cast<uint2*>((char*)(Th) + off) = hv;                 \
            *reinterpret_cast<uint2*>((char*)(Tl) + off) = lvv;                \
            float s = a0 * a0;                                                 \
            s = fmaf(a1, a1, s); s = fmaf(a2, a2, s); s = fmaf(a3, a3, s);     \
            s += __shfl_xor(s, 1);                                             \
            s += __shfl_xor(s, 2);                                             \
            s += __shfl_xor(s, 4);                                             \
            s += __shfl_xor(s, 8);                                             \
            if (kq == 0) (SQ)[row] = s;                                        \
        }                                                                      \
    }

    STAGE(x1b, Ah, Al, sqA)
    STAGE(x2b, Bh, Bl, sqB)
    __syncthreads();

    // ---- MFMA: 3 passes (hi.hi, hi.lo, lo.hi), K=64 each -----------------
    const int wid  = t >> 6;
    const int lane = t & 63;
    const int wr = wid >> 1, wc = wid & 1;   // wave's 64x64 quadrant
    const int fr = lane & 15;                // fragment row/col
    const int kg = lane >> 4;                // k-group 0..3

    f32x4 acc[4][4] = {};

    #pragma unroll
    for (int pass = 0; pass < 3; ++pass) {
        const ushort_t* TA = (pass == 2) ? Al : Ah;
        const ushort_t* TB = (pass == 1) ? Bl : Bh;
        #pragma unroll
        for (int kk = 0; kk < 2; ++kk) {
            s16x8 af[4], bg[4];
            #pragma unroll
            for (int m = 0; m < 4; ++m)
                af[m] = *reinterpret_cast<const s16x8*>(
                    (const char*)TA + swz16(wr * 64 + m * 16 + fr, kk * 4 + kg));
            #pragma unroll
            for (int n = 0; n < 4; ++n)
                bg[n] = *reinterpret_cast<const s16x8*>(
                    (const char*)TB + swz16(wc * 64 + n * 16 + fr, kk * 4 + kg));
            #pragma unroll
            for (int m = 0; m < 4; ++m)
                #pragma unroll
                for (int n = 0; n < 4; ++n)
                    acc[m][n] = __builtin_amdgcn_mfma_f32_16x16x32_bf16(
                        af[m], bg[n], acc[m][n], 0, 0, 0);
        }
    }

    // ---- epilogue: d2 -> matern -> store --------------------------------
    // C/D layout (m89-verified): col = lane&15, row = (lane>>4)*4 + reg.
    const float c0 = cc[0];
    const float c2 = c0 * c0;
    const float SQ5   = 2.23606797749979f;
    const float FIVE3 = 1.66666666666667f;

    #pragma unroll
    for (int m = 0; m < 4; ++m) {
        #pragma unroll
        for (int n = 0; n < 4; ++n) {
            f32x4 v = acc[m][n];
            const int col_l = wc * 64 + n * 16 + fr;
            const float sb = sqB[col_l];
            const size_t gcol = (size_t)(bj * TILE) + col_l;
            #pragma unroll
            for (int rg = 0; rg < 4; ++rg) {
                const int row_l = wr * 64 + m * 16 + kg * 4 + rg;
                const float sa = sqA[row_l];
                float d2 = fmaxf(sa + sb - 2.0f * v[rg], 0.0f);
                float rr = sqrtf(d2);
                float ee = __expf(-SQ5 * rr);
                float res = (c2 * fmaf(FIVE3, d2, fmaf(SQ5, rr, 1.0f))) * ee;
                out[((size_t)(bi * TILE) + row_l) * (size_t)N2 + gcol] = res;
            }
        }
    }
}

extern "C" void kernel_launch(void* const* d_in, const int* in_sizes, int n_in,
                              void* d_out, int out_size, void* d_ws, size_t ws_size,
                              hipStream_t stream) {
    const float* X1 = (const float*)d_in[0];
    const float* X2 = (const float*)d_in[1];
    const float* c  = (const float*)d_in[2];
    const float* l  = (const float*)d_in[3];
    float* out = (float*)d_out;

    const int N1 = in_sizes[0] / N_DIM;   // 8192
    const int N2 = in_sizes[1] / N_DIM;   // 8192

    dim3 grid(N2 / TILE, N1 / TILE);      // 64 x 64 blocks
    matern52_mfma_kernel<<<grid, 256, 0, stream>>>(X1, X2, c, l, out, N1, N2);
}

// Round 3
// 95.782 us; speedup vs baseline: 1.6970x; 1.1839x over previous
//
#include <hip/hip_runtime.h>
#include <math.h>

#define N_DIM 64
#define TILE  128

typedef unsigned short ushort_t;
typedef unsigned int   uint_t;
typedef short s16x8 __attribute__((ext_vector_type(8)));
typedef float f32x4 __attribute__((ext_vector_type(4)));

__device__ __forceinline__ ushort_t f2bf(float f) {          // round-to-nearest-even bf16
    uint_t u = __float_as_uint(f);
    u += 0x7FFFu + ((u >> 16) & 1u);
    return (ushort_t)(u >> 16);
}
__device__ __forceinline__ float bf2f(ushort_t h) {
    return __uint_as_float(((uint_t)h) << 16);
}

// Byte offset of 16B chunk kc (0..7) in row `row` of a [128][64] bf16 tile,
// XOR-swizzled so 16-lane column reads spread across 8 bank slots (G4).
__device__ __forceinline__ int swz16(int row, int kc) {
    return (row << 7) + ((kc << 4) ^ ((row & 7) << 4));
}

// Matern 5/2 via split-bf16 MFMA (hi.hi + hi.lo + lo.hi; lo.lo ~2^-18 dropped).
// 512 thr = 8 waves (4 row-strips x 2 col-strips), 128x128 tile, K=64 whole.
// MFMA operands SWAPPED (B-frag first) so each lane's 4 acc regs are 4
// consecutive output COLUMNS of one row -> global_store_dwordx4.
__global__ __launch_bounds__(512, 4)
void matern52_mfma_kernel(const float* __restrict__ X1,
                          const float* __restrict__ X2,
                          const float* __restrict__ cc,
                          const float* __restrict__ l,
                          float* __restrict__ out,
                          int N1, int N2)
{
    __shared__ ushort_t Ah[TILE * N_DIM], Al[TILE * N_DIM];
    __shared__ ushort_t Bh[TILE * N_DIM], Bl[TILE * N_DIM];
    __shared__ float sqA[TILE], sqB[TILE];

    const int t  = threadIdx.x;
    const int bi = blockIdx.y, bj = blockIdx.x;

    const int kq   = t & 15;           // float4 index within a 64-dim row
    const int rsub = t >> 4;           // row sub-index 0..31

    float4 lv = *reinterpret_cast<const float4*>(&l[kq * 4]);
    const float rlx = 1.f / lv.x, rly = 1.f / lv.y, rlz = 1.f / lv.z, rlw = 1.f / lv.w;

    const float* x1b = X1 + (size_t)(bi * TILE) * N_DIM;
    const float* x2b = X2 + (size_t)(bj * TILE) * N_DIM;

    // ---- stage: fp32 -> (hi,lo) bf16 tiles + row norms (4 iters x 32 rows) --
    #define STAGE(Xb, Th, Tl, SQ)                                              \
    {                                                                          \
        _Pragma("unroll")                                                      \
        for (int c = 0; c < 4; ++c) {                                          \
            const int row = c * 32 + rsub;                                     \
            float4 x = *reinterpret_cast<const float4*>(&(Xb)[row * N_DIM + kq * 4]); \
            float a0 = x.x * rlx, a1 = x.y * rly, a2 = x.z * rlz, a3 = x.w * rlw; \
            ushort_t h0 = f2bf(a0), h1 = f2bf(a1), h2 = f2bf(a2), h3 = f2bf(a3); \
            ushort_t e0 = f2bf(a0 - bf2f(h0)), e1 = f2bf(a1 - bf2f(h1));       \
            ushort_t e2 = f2bf(a2 - bf2f(h2)), e3 = f2bf(a3 - bf2f(h3));       \
            const int off = (row << 7) + (((kq >> 1) << 4) ^ ((row & 7) << 4)) + ((kq & 1) << 3); \
            uint2 hv, lvv;                                                     \
            hv.x  = (uint_t)h0 | ((uint_t)h1 << 16);                           \
            hv.y  = (uint_t)h2 | ((uint_t)h3 << 16);                           \
            lvv.x = (uint_t)e0 | ((uint_t)e1 << 16);                           \
            lvv.y = (uint_t)e2 | ((uint_t)e3 << 16);                           \
            *reinterpret_cast<uint2*>((char*)(Th) + off) = hv;                 \
            *reinterpret_cast<uint2*>((char*)(Tl) + off) = lvv;                \
            float s = a0 * a0;                                                 \
            s = fmaf(a1, a1, s); s = fmaf(a2, a2, s); s = fmaf(a3, a3, s);     \
            s += __shfl_xor(s, 1);                                             \
            s += __shfl_xor(s, 2);                                             \
            s += __shfl_xor(s, 4);                                             \
            s += __shfl_xor(s, 8);                                             \
            if (kq == 0) (SQ)[row] = s;                                        \
        }                                                                      \
    }

    STAGE(x1b, Ah, Al, sqA)
    STAGE(x2b, Bh, Bl, sqB)
    __syncthreads();

    // ---- MFMA: 3 passes (hi.hi, hi.lo, lo.hi), K=64 each --------------------
    const int wid  = t >> 6;           // 0..7
    const int lane = t & 63;
    const int wtr = wid >> 1;          // 0..3 : 32-row strip
    const int wtc = wid & 1;           // 0..1 : 64-col strip
    const int fr  = lane & 15;
    const int kg  = lane >> 4;

    f32x4 acc[2][4] = {};              // [m: 16-row sub][n: 16-col sub]

    #pragma unroll
    for (int pass = 0; pass < 3; ++pass) {
        const ushort_t* TA = (pass == 2) ? Al : Ah;
        const ushort_t* TB = (pass == 1) ? Bl : Bh;
        #pragma unroll
        for (int kk = 0; kk < 2; ++kk) {
            s16x8 af[2], bg[4];
            #pragma unroll
            for (int m = 0; m < 2; ++m)
                af[m] = *reinterpret_cast<const s16x8*>(
                    (const char*)TA + swz16(wtr * 32 + m * 16 + fr, kk * 4 + kg));
            #pragma unroll
            for (int n = 0; n < 4; ++n)
                bg[n] = *reinterpret_cast<const s16x8*>(
                    (const char*)TB + swz16(wtc * 64 + n * 16 + fr, kk * 4 + kg));
            // Swapped operands: first-arg matrix row -> (lane>>4)*4+reg = out COL,
            // second-arg matrix row -> lane&15 = out ROW  (verified round 2).
            #pragma unroll
            for (int m = 0; m < 2; ++m)
                #pragma unroll
                for (int n = 0; n < 4; ++n)
                    acc[m][n] = __builtin_amdgcn_mfma_f32_16x16x32_bf16(
                        bg[n], af[m], acc[m][n], 0, 0, 0);
        }
    }

    // ---- epilogue: lane (fr,kg) owns out[m*16+fr][n*16+kg*4 .. +3] ----------
    const float c0 = cc[0];
    const float SQ5   = 2.23606797749979f;
    const float FIVE3 = 1.66666666666667f;
    const float lnc2  = 2.0f * __logf(c0);     // fold c^2 into the exponent

    #pragma unroll
    for (int m = 0; m < 2; ++m) {
        const int row_l = wtr * 32 + m * 16 + fr;
        const float sa = sqA[row_l];
        float* rowp = out + ((size_t)(bi * TILE) + row_l) * (size_t)N2
                          + (size_t)(bj * TILE) + wtc * 64;
        #pragma unroll
        for (int n = 0; n < 4; ++n) {
            const int cb = n * 16 + kg * 4;
            f32x4 sb4 = *reinterpret_cast<const f32x4*>(&sqB[wtc * 64 + cb]);
            f32x4 v = acc[m][n];
            f32x4 res;
            #pragma unroll
            for (int q = 0; q < 4; ++q) {
                float d2 = fmaxf(fmaf(-2.0f, v[q], sa + sb4[q]), 0.0f);
                float r  = sqrtf(d2);
                float e  = __expf(fmaf(-SQ5, r, lnc2));      // c2 * exp(-s5 r)
                res[q] = fmaf(FIVE3, d2, fmaf(SQ5, r, 1.0f)) * e;
            }
            *reinterpret_cast<f32x4*>(rowp + cb) = res;
        }
    }
}

extern "C" void kernel_launch(void* const* d_in, const int* in_sizes, int n_in,
                              void* d_out, int out_size, void* d_ws, size_t ws_size,
                              hipStream_t stream) {
    const float* X1 = (const float*)d_in[0];
    const float* X2 = (const float*)d_in[1];
    const float* c  = (const float*)d_in[2];
    const float* l  = (const float*)d_in[3];
    float* out = (float*)d_out;

    const int N1 = in_sizes[0] / N_DIM;   // 8192
    const int N2 = in_sizes[1] / N_DIM;   // 8192

    dim3 grid(N2 / TILE, N1 / TILE);      // 64 x 64 blocks
    matern52_mfma_kernel<<<grid, 512, 0, stream>>>(X1, X2, c, l, out, N1, N2);
}

// Round 4
// 66.361 us; speedup vs baseline: 2.4494x; 1.4434x over previous
//
#include <hip/hip_runtime.h>
#include <math.h>

#define N_DIM 64
#define TILE  128

typedef unsigned short ushort_t;
typedef unsigned int   uint_t;
typedef short    s16x8 __attribute__((ext_vector_type(8)));
typedef _Float16 f16x8 __attribute__((ext_vector_type(8)));
typedef _Float16 f16x4 __attribute__((ext_vector_type(4)));
typedef float    f32x4 __attribute__((ext_vector_type(4)));

// ---------------------------------------------------------------------------
// Shared helpers
// ---------------------------------------------------------------------------
__device__ __forceinline__ ushort_t f2bf(float f) {          // RNE bf16 (fallback path)
    uint_t u = __float_as_uint(f);
    u += 0x7FFFu + ((u >> 16) & 1u);
    return (ushort_t)(u >> 16);
}
__device__ __forceinline__ float bf2f(ushort_t h) {
    return __uint_as_float(((uint_t)h) << 16);
}

// Byte offset of 16B chunk kc (0..7) in row `row` of a [128 x 128B] tile,
// XOR-swizzled (G4): spreads 8 consecutive rows' same-kc chunks over 8 banksets.
__device__ __forceinline__ int swz16(int row, int kc) {
    return (row << 7) + ((kc ^ (row & 7)) << 4);
}

// global -> LDS direct copy, 16B per lane. LDS dest = wave-uniform base + lane*16.
typedef __attribute__((address_space(1))) const void gas_void;
typedef __attribute__((address_space(3))) void       las_void;
__device__ __forceinline__ void gload16(const void* g, void* l) {
    __builtin_amdgcn_global_load_lds((gas_void*)g, (las_void*)l, 16, 0, 0);
}

// ---------------------------------------------------------------------------
// Prep kernel: X -> fp16(x/l) tiles in ws (XOR-pre-permuted so the main
// kernel's LINEAR global_load_lds yields the swizzled LDS layout), plus exact
// fp32 row norms. 16 lanes per row, 16 rows per 256-thread block.
// ---------------------------------------------------------------------------
__global__ __launch_bounds__(256)
void matern52_prep_kernel(const float* __restrict__ X,
                          const float* __restrict__ l,
                          unsigned char* __restrict__ dst,
                          float* __restrict__ sq, int N)
{
    const int t   = threadIdx.x;
    const int kq  = t & 15;                      // float4 index in the 64-dim row
    const int row = blockIdx.x * 16 + (t >> 4);

    float4 lv = *reinterpret_cast<const float4*>(&l[kq * 4]);
    float4 x  = *reinterpret_cast<const float4*>(&X[(size_t)row * N_DIM + kq * 4]);
    // exact division: matches ref's X / l
    const float a0 = x.x / lv.x, a1 = x.y / lv.y, a2 = x.z / lv.z, a3 = x.w / lv.w;

    // fp32 row norm (16-lane shfl reduce)
    float s = a0 * a0;
    s = fmaf(a1, a1, s); s = fmaf(a2, a2, s); s = fmaf(a3, a3, s);
    s += __shfl_xor(s, 1);
    s += __shfl_xor(s, 2);
    s += __shfl_xor(s, 4);
    s += __shfl_xor(s, 8);
    if (kq == 0) sq[row] = s;

    // fp16 RNE convert, write to XOR-permuted chunk: ws chunk (row, j) holds
    // source chunk j^(row&7)  ->  linear LDS fill + swizzled ds_read is exact.
    f16x4 h = { (_Float16)a0, (_Float16)a1, (_Float16)a2, (_Float16)a3 };
    const int off = (row << 7) + ((((kq >> 1) ^ (row & 7))) << 4) + ((kq & 1) << 3);
    *reinterpret_cast<f16x4*>(dst + off) = h;
}

// ---------------------------------------------------------------------------
// Main kernel: 512 thr = 8 waves (4 row-strips x 2 col-strips), 128x128 tile.
// Stage pre-split fp16 tiles via global_load_lds (linear), 1-pass K=64 MFMA,
// matern epilogue with dwordx4 stores (operand-swapped MFMA, verified r2/r3).
// ---------------------------------------------------------------------------
__global__ __launch_bounds__(512, 4)
void matern52_main_kernel(const unsigned char* __restrict__ A16,
                          const unsigned char* __restrict__ B16,
                          const float* __restrict__ sq1,
                          const float* __restrict__ sq2,
                          const float* __restrict__ cc,
                          float* __restrict__ out,
                          int N1, int N2)
{
    __shared__ __align__(16) unsigned char lds[2 * TILE * N_DIM * 2]; // A:16KB | B:16KB

    const int t  = threadIdx.x;
    const int bi = blockIdx.y, bj = blockIdx.x;

    unsigned char* ldsA = lds;
    unsigned char* ldsB = lds + TILE * N_DIM * 2;

    // ---- stage: 4x global_load_lds dwordx4 per thread ----------------------
    {
        const unsigned char* srcA = A16 + (size_t)bi * (TILE * N_DIM * 2);
        const unsigned char* srcB = B16 + (size_t)bj * (TILE * N_DIM * 2);
        const int wbase = (t & ~63) * 16;        // wave-uniform LDS byte base
        const int lbyte = t * 16;                // = wbase + lane*16
        gload16(srcA + lbyte,        ldsA + wbase);
        gload16(srcA + 8192 + lbyte, ldsA + 8192 + wbase);
        gload16(srcB + lbyte,        ldsB + wbase);
        gload16(srcB + 8192 + lbyte, ldsB + 8192 + wbase);
    }
    __syncthreads();

    // ---- 1-pass fp16 MFMA, K=64 -------------------------------------------
    const int wid  = t >> 6;          // 0..7
    const int lane = t & 63;
    const int wtr  = wid >> 1;        // 0..3 : 32-row strip
    const int wtc  = wid & 1;         // 0..1 : 64-col strip
    const int fr   = lane & 15;
    const int kg   = lane >> 4;

    f32x4 acc[2][4] = {};

    #pragma unroll
    for (int kk = 0; kk < 2; ++kk) {
        f16x8 af[2], bg[4];
        #pragma unroll
        for (int m = 0; m < 2; ++m)
            af[m] = *reinterpret_cast<const f16x8*>(
                ldsA + swz16(wtr * 32 + m * 16 + fr, kk * 4 + kg));
        #pragma unroll
        for (int n = 0; n < 4; ++n)
            bg[n] = *reinterpret_cast<const f16x8*>(
                ldsB + swz16(wtc * 64 + n * 16 + fr, kk * 4 + kg));
        // swapped operands (r3-verified): lane fr -> out row, reg -> out col
        #pragma unroll
        for (int m = 0; m < 2; ++m)
            #pragma unroll
            for (int n = 0; n < 4; ++n)
                acc[m][n] = __builtin_amdgcn_mfma_f32_16x16x32_f16(
                    bg[n], af[m], acc[m][n], 0, 0, 0);
    }

    // ---- epilogue: lane (fr,kg) owns out[..+fr][n*16+kg*4 .. +3] -----------
    const float c0 = cc[0];
    const float SQ5   = 2.23606797749979f;
    const float FIVE3 = 1.66666666666667f;
    const float lnc2  = 2.0f * __logf(c0);

    const float* sqA = sq1 + bi * TILE;
    const float* sqB = sq2 + bj * TILE + wtc * 64;

    #pragma unroll
    for (int m = 0; m < 2; ++m) {
        const int row_l = wtr * 32 + m * 16 + fr;
        const float sa = sqA[row_l];
        float* rowp = out + ((size_t)(bi * TILE) + row_l) * (size_t)N2
                          + (size_t)(bj * TILE) + wtc * 64;
        #pragma unroll
        for (int n = 0; n < 4; ++n) {
            const int cb = n * 16 + kg * 4;
            f32x4 sb4 = *reinterpret_cast<const f32x4*>(sqB + cb);
            f32x4 v = acc[m][n];
            f32x4 res;
            #pragma unroll
            for (int q = 0; q < 4; ++q) {
                float d2 = fmaxf(fmaf(-2.0f, v[q], sa + sb4[q]), 0.0f);
                float r  = sqrtf(d2);
                float e  = __expf(fmaf(-SQ5, r, lnc2));      // c2 * exp(-s5 r)
                res[q] = fmaf(FIVE3, d2, fmaf(SQ5, r, 1.0f)) * e;
            }
            *reinterpret_cast<f32x4*>(rowp + cb) = res;
        }
    }
}

// ---------------------------------------------------------------------------
// Fallback (ws too small): round-3 verified split-bf16 kernel, self-contained.
// ---------------------------------------------------------------------------
__global__ __launch_bounds__(512, 4)
void matern52_fallback_kernel(const float* __restrict__ X1,
                              const float* __restrict__ X2,
                              const float* __restrict__ cc,
                              const float* __restrict__ l,
                              float* __restrict__ out,
                              int N1, int N2)
{
    __shared__ ushort_t Ah[TILE * N_DIM], Al[TILE * N_DIM];
    __shared__ ushort_t Bh[TILE * N_DIM], Bl[TILE * N_DIM];
    __shared__ float sqA[TILE], sqB[TILE];

    const int t  = threadIdx.x;
    const int bi = blockIdx.y, bj = blockIdx.x;
    const int kq   = t & 15;
    const int rsub = t >> 4;

    float4 lv = *reinterpret_cast<const float4*>(&l[kq * 4]);
    const float rlx = 1.f / lv.x, rly = 1.f / lv.y, rlz = 1.f / lv.z, rlw = 1.f / lv.w;
    const float* x1b = X1 + (size_t)(bi * TILE) * N_DIM;
    const float* x2b = X2 + (size_t)(bj * TILE) * N_DIM;

    #define STAGE(Xb, Th, Tl, SQ)                                              \
    {                                                                          \
        _Pragma("unroll")                                                      \
        for (int c = 0; c < 4; ++c) {                                          \
            const int row = c * 32 + rsub;                                     \
            float4 x = *reinterpret_cast<const float4*>(&(Xb)[row * N_DIM + kq * 4]); \
            float a0 = x.x * rlx, a1 = x.y * rly, a2 = x.z * rlz, a3 = x.w * rlw; \
            ushort_t h0 = f2bf(a0), h1 = f2bf(a1), h2 = f2bf(a2), h3 = f2bf(a3); \
            ushort_t e0 = f2bf(a0 - bf2f(h0)), e1 = f2bf(a1 - bf2f(h1));       \
            ushort_t e2 = f2bf(a2 - bf2f(h2)), e3 = f2bf(a3 - bf2f(h3));       \
            const int off = (row << 7) + (((kq >> 1) << 4) ^ ((row & 7) << 4)) + ((kq & 1) << 3); \
            uint2 hv, lvv;                                                     \
            hv.x  = (uint_t)h0 | ((uint_t)h1 << 16);                           \
            hv.y  = (uint_t)h2 | ((uint_t)h3 << 16);                           \
            lvv.x = (uint_t)e0 | ((uint_t)e1 << 16);                           \
            lvv.y = (uint_t)e2 | ((uint_t)e3 << 16);                           \
            *reinterpret_cast<uint2*>((char*)(Th) + off) = hv;                 \
            *reinterpret_cast<uint2*>((char*)(Tl) + off) = lvv;                \
            float s = a0 * a0;                                                 \
            s = fmaf(a1, a1, s); s = fmaf(a2, a2, s); s = fmaf(a3, a3, s);     \
            s += __shfl_xor(s, 1);                                             \
            s += __shfl_xor(s, 2);                                             \
            s += __shfl_xor(s, 4);                                             \
            s += __shfl_xor(s, 8);                                             \
            if (kq == 0) (SQ)[row] = s;                                        \
        }                                                                      \
    }
    STAGE(x1b, Ah, Al, sqA)
    STAGE(x2b, Bh, Bl, sqB)
    #undef STAGE
    __syncthreads();

    const int wid  = t >> 6;
    const int lane = t & 63;
    const int wtr = wid >> 1, wtc = wid & 1;
    const int fr  = lane & 15, kg = lane >> 4;

    f32x4 acc[2][4] = {};
    #pragma unroll
    for (int pass = 0; pass < 3; ++pass) {
        const ushort_t* TA = (pass == 2) ? Al : Ah;
        const ushort_t* TB = (pass == 1) ? Bl : Bh;
        #pragma unroll
        for (int kk = 0; kk < 2; ++kk) {
            s16x8 af[2], bg[4];
            #pragma unroll
            for (int m = 0; m < 2; ++m)
                af[m] = *reinterpret_cast<const s16x8*>(
                    (const char*)TA + swz16(wtr * 32 + m * 16 + fr, kk * 4 + kg));
            #pragma unroll
            for (int n = 0; n < 4; ++n)
                bg[n] = *reinterpret_cast<const s16x8*>(
                    (const char*)TB + swz16(wtc * 64 + n * 16 + fr, kk * 4 + kg));
            #pragma unroll
            for (int m = 0; m < 2; ++m)
                #pragma unroll
                for (int n = 0; n < 4; ++n)
                    acc[m][n] = __builtin_amdgcn_mfma_f32_16x16x32_bf16(
                        bg[n], af[m], acc[m][n], 0, 0, 0);
        }
    }

    const float c0 = cc[0];
    const float SQ5   = 2.23606797749979f;
    const float FIVE3 = 1.66666666666667f;
    const float lnc2  = 2.0f * __logf(c0);

    #pragma unroll
    for (int m = 0; m < 2; ++m) {
        const int row_l = wtr * 32 + m * 16 + fr;
        const float sa = sqA[row_l];
        float* rowp = out + ((size_t)(bi * TILE) + row_l) * (size_t)N2
                          + (size_t)(bj * TILE) + wtc * 64;
        #pragma unroll
        for (int n = 0; n < 4; ++n) {
            const int cb = n * 16 + kg * 4;
            f32x4 sb4 = *reinterpret_cast<const f32x4*>(&sqB[wtc * 64 + cb]);
            f32x4 v = acc[m][n];
            f32x4 res;
            #pragma unroll
            for (int q = 0; q < 4; ++q) {
                float d2 = fmaxf(fmaf(-2.0f, v[q], sa + sb4[q]), 0.0f);
                float r  = sqrtf(d2);
                float e  = __expf(fmaf(-SQ5, r, lnc2));
                res[q] = fmaf(FIVE3, d2, fmaf(SQ5, r, 1.0f)) * e;
            }
            *reinterpret_cast<f32x4*>(rowp + cb) = res;
        }
    }
}

extern "C" void kernel_launch(void* const* d_in, const int* in_sizes, int n_in,
                              void* d_out, int out_size, void* d_ws, size_t ws_size,
                              hipStream_t stream) {
    const float* X1 = (const float*)d_in[0];
    const float* X2 = (const float*)d_in[1];
    const float* c  = (const float*)d_in[2];
    const float* l  = (const float*)d_in[3];
    float* out = (float*)d_out;

    const int N1 = in_sizes[0] / N_DIM;   // 8192
    const int N2 = in_sizes[1] / N_DIM;   // 8192

    const size_t rowBytes = (size_t)N_DIM * 2 * TILE / TILE; // 128 B per row
    const size_t aBytes   = (size_t)N1 * 128;
    const size_t bBytes   = (size_t)N2 * 128;
    const size_t needWs   = aBytes + bBytes + (size_t)(N1 + N2) * sizeof(float);
    (void)rowBytes;

    dim3 grid(N2 / TILE, N1 / TILE);      // 64 x 64 blocks

    if (ws_size >= needWs) {
        unsigned char* A16 = (unsigned char*)d_ws;
        unsigned char* B16 = A16 + aBytes;
        float* sq1 = (float*)(B16 + bBytes);
        float* sq2 = sq1 + N1;

        matern52_prep_kernel<<<dim3(N1 / 16), 256, 0, stream>>>(X1, l, A16, sq1, N1);
        matern52_prep_kernel<<<dim3(N2 / 16), 256, 0, stream>>>(X2, l, B16, sq2, N2);
        matern52_main_kernel<<<grid, 512, 0, stream>>>(A16, B16, sq1, sq2, c, out, N1, N2);
    } else {
        matern52_fallback_kernel<<<grid, 512, 0, stream>>>(X1, X2, c, l, out, N1, N2);
    }
}

// Round 5
// 58.131 us; speedup vs baseline: 2.7962x; 1.1416x over previous
//
#include <hip/hip_runtime.h>
#include <math.h>

#define N_DIM 64
#define TILE  128

typedef unsigned short ushort_t;
typedef unsigned int   uint_t;
typedef _Float16 f16x8 __attribute__((ext_vector_type(8)));
typedef _Float16 f16x4 __attribute__((ext_vector_type(4)));
typedef float    f32x4 __attribute__((ext_vector_type(4)));

// ---------------------------------------------------------------------------
// Byte offset of 16B chunk kc (0..7) in row `row` of a [128 x 128B] tile,
// XOR-swizzled (G4): spreads 8 consecutive rows' same-kc chunks over 8 banksets.
__device__ __forceinline__ int swz16(int row, int kc) {
    return (row << 7) + ((kc ^ (row & 7)) << 4);
}

// global -> LDS direct copy, 16B per lane. LDS dest = wave-uniform base + lane*16.
typedef __attribute__((address_space(1))) const void gas_void;
typedef __attribute__((address_space(3))) void       las_void;
__device__ __forceinline__ void gload16(const void* g, void* l) {
    __builtin_amdgcn_global_load_lds((gas_void*)g, (las_void*)l, 16, 0, 0);
}

// ---------------------------------------------------------------------------
// Prep: X -> fp16(x/l), XOR-pre-permuted so the main kernel's LINEAR
// global_load_lds lands in swizzled LDS layout; exact fp32 row norms.
// ---------------------------------------------------------------------------
__global__ __launch_bounds__(256)
void matern52_prep_kernel(const float* __restrict__ X,
                          const float* __restrict__ l,
                          unsigned char* __restrict__ dst,
                          float* __restrict__ sq, int N)
{
    const int t   = threadIdx.x;
    const int kq  = t & 15;
    const int row = blockIdx.x * 16 + (t >> 4);

    float4 lv = *reinterpret_cast<const float4*>(&l[kq * 4]);
    float4 x  = *reinterpret_cast<const float4*>(&X[(size_t)row * N_DIM + kq * 4]);
    const float a0 = x.x / lv.x, a1 = x.y / lv.y, a2 = x.z / lv.z, a3 = x.w / lv.w;

    float s = a0 * a0;
    s = fmaf(a1, a1, s); s = fmaf(a2, a2, s); s = fmaf(a3, a3, s);
    s += __shfl_xor(s, 1);
    s += __shfl_xor(s, 2);
    s += __shfl_xor(s, 4);
    s += __shfl_xor(s, 8);
    if (kq == 0) sq[row] = s;

    f16x4 h = { (_Float16)a0, (_Float16)a1, (_Float16)a2, (_Float16)a3 };
    const int off = (row << 7) + ((((kq >> 1) ^ (row & 7))) << 4) + ((kq & 1) << 3);
    *reinterpret_cast<f16x4*>(dst + off) = h;
}

// ---------------------------------------------------------------------------
// Main: 256 thr = 4 waves (2x2 quadrants of a 128x128 tile). Stage via
// global_load_lds, 1-pass K=64 fp16 MFMA (operand-swapped: reg idx -> out
// col, lane&15 -> out row; verified r2-r4), matern epilogue, dwordx4 stores.
// 4 blocks/CU (VGPR<=128, LDS 32KB) for store-drain phase stagger.
// ---------------------------------------------------------------------------
__global__ __launch_bounds__(256, 4)
void matern52_main_kernel(const unsigned char* __restrict__ A16,
                          const unsigned char* __restrict__ B16,
                          const float* __restrict__ sq1,
                          const float* __restrict__ sq2,
                          const float* __restrict__ cc,
                          float* __restrict__ out,
                          int N1, int N2)
{
    __shared__ __align__(16) unsigned char lds[2 * TILE * N_DIM * 2]; // A:16KB | B:16KB

    const int t  = threadIdx.x;
    const int bi = blockIdx.y, bj = blockIdx.x;

    unsigned char* ldsA = lds;
    unsigned char* ldsB = lds + TILE * N_DIM * 2;

    // ---- stage: 8x global_load_lds dwordx4 per thread ----------------------
    {
        const unsigned char* srcA = A16 + (size_t)bi * (TILE * N_DIM * 2);
        const unsigned char* srcB = B16 + (size_t)bj * (TILE * N_DIM * 2);
        const int wbase = (t >> 6) << 10;       // wave-uniform LDS byte base
        const int gb    = t * 16;
        #pragma unroll
        for (int i = 0; i < 4; ++i) {
            gload16(srcA + i * 4096 + gb, ldsA + i * 4096 + wbase);
            gload16(srcB + i * 4096 + gb, ldsB + i * 4096 + wbase);
        }
    }
    __syncthreads();

    // ---- 1-pass fp16 MFMA, K=64 -------------------------------------------
    const int wid  = t >> 6;          // 0..3
    const int lane = t & 63;
    const int wtr  = wid >> 1;        // 0..1 : 64-row strip
    const int wtc  = wid & 1;         // 0..1 : 64-col strip
    const int fr   = lane & 15;
    const int kg   = lane >> 4;

    f32x4 acc[4][4] = {};

    #pragma unroll
    for (int kk = 0; kk < 2; ++kk) {
        f16x8 af[4], bg[4];
        #pragma unroll
        for (int m = 0; m < 4; ++m)
            af[m] = *reinterpret_cast<const f16x8*>(
                ldsA + swz16(wtr * 64 + m * 16 + fr, kk * 4 + kg));
        #pragma unroll
        for (int n = 0; n < 4; ++n)
            bg[n] = *reinterpret_cast<const f16x8*>(
                ldsB + swz16(wtc * 64 + n * 16 + fr, kk * 4 + kg));
        #pragma unroll
        for (int m = 0; m < 4; ++m)
            #pragma unroll
            for (int n = 0; n < 4; ++n)
                acc[m][n] = __builtin_amdgcn_mfma_f32_16x16x32_f16(
                    bg[n], af[m], acc[m][n], 0, 0, 0);
    }

    // ---- epilogue ----------------------------------------------------------
    // exp folded to exp2: out = poly(r,d2) * 2^(log2(c^2) - s5*log2e * r)
    const float c0 = cc[0];
    const float SQ5    = 2.23606797749979f;
    const float FIVE3  = 1.66666666666667f;
    const float NK     = -3.22617785847899f;          // -sqrt5 * log2(e)
    const float l2c2   = 2.885390081777927f * __logf(c0); // 2*log2(c0)

    const float* sqA = sq1 + bi * TILE;
    const float* sqB = sq2 + bj * TILE + wtc * 64;

    #pragma unroll
    for (int m = 0; m < 4; ++m) {
        const int row_l = wtr * 64 + m * 16 + fr;
        const float sa = sqA[row_l];
        float* rowp = out + ((size_t)(bi * TILE) + row_l) * (size_t)N2
                          + (size_t)(bj * TILE) + wtc * 64;
        #pragma unroll
        for (int n = 0; n < 4; ++n) {
            const int cb = n * 16 + kg * 4;
            f32x4 sb4 = *reinterpret_cast<const f32x4*>(sqB + cb);
            f32x4 v = acc[m][n];
            f32x4 res;
            #pragma unroll
            for (int q = 0; q < 4; ++q) {
                float d2 = fmaxf(fmaf(-2.0f, v[q], sa + sb4[q]), 0.0f);
                float r  = __builtin_amdgcn_sqrtf(d2);          // raw v_sqrt_f32
                float e  = __builtin_amdgcn_exp2f(fmaf(NK, r, l2c2)); // raw v_exp_f32
                res[q] = fmaf(FIVE3, d2, fmaf(SQ5, r, 1.0f)) * e;
            }
            *reinterpret_cast<f32x4*>(rowp + cb) = res;
        }
    }
}

// ---------------------------------------------------------------------------
// Fallback (ws too small): self-contained split-bf16 (round-3 verified).
// ---------------------------------------------------------------------------
__device__ __forceinline__ ushort_t f2bf(float f) {
    uint_t u = __float_as_uint(f);
    u += 0x7FFFu + ((u >> 16) & 1u);
    return (ushort_t)(u >> 16);
}
__device__ __forceinline__ float bf2f(ushort_t h) {
    return __uint_as_float(((uint_t)h) << 16);
}
typedef short s16x8 __attribute__((ext_vector_type(8)));

__global__ __launch_bounds__(512, 4)
void matern52_fallback_kernel(const float* __restrict__ X1,
                              const float* __restrict__ X2,
                              const float* __restrict__ cc,
                              const float* __restrict__ l,
                              float* __restrict__ out,
                              int N1, int N2)
{
    __shared__ ushort_t Ah[TILE * N_DIM], Al[TILE * N_DIM];
    __shared__ ushort_t Bh[TILE * N_DIM], Bl[TILE * N_DIM];
    __shared__ float sqA[TILE], sqB[TILE];

    const int t  = threadIdx.x;
    const int bi = blockIdx.y, bj = blockIdx.x;
    const int kq   = t & 15;
    const int rsub = t >> 4;

    float4 lv = *reinterpret_cast<const float4*>(&l[kq * 4]);
    const float rlx = 1.f / lv.x, rly = 1.f / lv.y, rlz = 1.f / lv.z, rlw = 1.f / lv.w;
    const float* x1b = X1 + (size_t)(bi * TILE) * N_DIM;
    const float* x2b = X2 + (size_t)(bj * TILE) * N_DIM;

    #define STAGE(Xb, Th, Tl, SQ)                                              \
    {                                                                          \
        _Pragma("unroll")                                                      \
        for (int c = 0; c < 4; ++c) {                                          \
            const int row = c * 32 + rsub;                                     \
            float4 x = *reinterpret_cast<const float4*>(&(Xb)[row * N_DIM + kq * 4]); \
            float a0 = x.x * rlx, a1 = x.y * rly, a2 = x.z * rlz, a3 = x.w * rlw; \
            ushort_t h0 = f2bf(a0), h1 = f2bf(a1), h2 = f2bf(a2), h3 = f2bf(a3); \
            ushort_t e0 = f2bf(a0 - bf2f(h0)), e1 = f2bf(a1 - bf2f(h1));       \
            ushort_t e2 = f2bf(a2 - bf2f(h2)), e3 = f2bf(a3 - bf2f(h3));       \
            const int off = (row << 7) + (((kq >> 1) << 4) ^ ((row & 7) << 4)) + ((kq & 1) << 3); \
            uint2 hv, lvv;                                                     \
            hv.x  = (uint_t)h0 | ((uint_t)h1 << 16);                           \
            hv.y  = (uint_t)h2 | ((uint_t)h3 << 16);                           \
            lvv.x = (uint_t)e0 | ((uint_t)e1 << 16);                           \
            lvv.y = (uint_t)e2 | ((uint_t)e3 << 16);                           \
            *reinterpret_cast<uint2*>((char*)(Th) + off) = hv;                 \
            *reinterpret_cast<uint2*>((char*)(Tl) + off) = lvv;                \
            float s = a0 * a0;                                                 \
            s = fmaf(a1, a1, s); s = fmaf(a2, a2, s); s = fmaf(a3, a3, s);     \
            s += __shfl_xor(s, 1);                                             \
            s += __shfl_xor(s, 2);                                             \
            s += __shfl_xor(s, 4);                                             \
            s += __shfl_xor(s, 8);                                             \
            if (kq == 0) (SQ)[row] = s;                                        \
        }                                                                      \
    }
    STAGE(x1b, Ah, Al, sqA)
    STAGE(x2b, Bh, Bl, sqB)
    #undef STAGE
    __syncthreads();

    const int wid  = t >> 6;
    const int lane = t & 63;
    const int wtr = wid >> 1, wtc = wid & 1;
    const int fr  = lane & 15, kg = lane >> 4;

    f32x4 acc[2][4] = {};
    #pragma unroll
    for (int pass = 0; pass < 3; ++pass) {
        const ushort_t* TA = (pass == 2) ? Al : Ah;
        const ushort_t* TB = (pass == 1) ? Bl : Bh;
        #pragma unroll
        for (int kk = 0; kk < 2; ++kk) {
            s16x8 af[2], bg[4];
            #pragma unroll
            for (int m = 0; m < 2; ++m)
                af[m] = *reinterpret_cast<const s16x8*>(
                    (const char*)TA + swz16(wtr * 32 + m * 16 + fr, kk * 4 + kg));
            #pragma unroll
            for (int n = 0; n < 4; ++n)
                bg[n] = *reinterpret_cast<const s16x8*>(
                    (const char*)TB + swz16(wtc * 64 + n * 16 + fr, kk * 4 + kg));
            #pragma unroll
            for (int m = 0; m < 2; ++m)
                #pragma unroll
                for (int n = 0; n < 4; ++n)
                    acc[m][n] = __builtin_amdgcn_mfma_f32_16x16x32_bf16(
                        bg[n], af[m], acc[m][n], 0, 0, 0);
        }
    }

    const float c0 = cc[0];
    const float SQ5   = 2.23606797749979f;
    const float FIVE3 = 1.66666666666667f;
    const float lnc2  = 2.0f * __logf(c0);

    #pragma unroll
    for (int m = 0; m < 2; ++m) {
        const int row_l = wtr * 32 + m * 16 + fr;
        const float sa = sqA[row_l];
        float* rowp = out + ((size_t)(bi * TILE) + row_l) * (size_t)N2
                          + (size_t)(bj * TILE) + wtc * 64;
        #pragma unroll
        for (int n = 0; n < 4; ++n) {
            const int cb = n * 16 + kg * 4;
            f32x4 sb4 = *reinterpret_cast<const f32x4*>(&sqB[wtc * 64 + cb]);
            f32x4 v = acc[m][n];
            f32x4 res;
            #pragma unroll
            for (int q = 0; q < 4; ++q) {
                float d2 = fmaxf(fmaf(-2.0f, v[q], sa + sb4[q]), 0.0f);
                float r  = sqrtf(d2);
                float e  = __expf(fmaf(-SQ5, r, lnc2));
                res[q] = fmaf(FIVE3, d2, fmaf(SQ5, r, 1.0f)) * e;
            }
            *reinterpret_cast<f32x4*>(rowp + cb) = res;
        }
    }
}

extern "C" void kernel_launch(void* const* d_in, const int* in_sizes, int n_in,
                              void* d_out, int out_size, void* d_ws, size_t ws_size,
                              hipStream_t stream) {
    const float* X1 = (const float*)d_in[0];
    const float* X2 = (const float*)d_in[1];
    const float* c  = (const float*)d_in[2];
    const float* l  = (const float*)d_in[3];
    float* out = (float*)d_out;

    const int N1 = in_sizes[0] / N_DIM;   // 8192
    const int N2 = in_sizes[1] / N_DIM;   // 8192

    const size_t aBytes = (size_t)N1 * 128;
    const size_t bBytes = (size_t)N2 * 128;
    const size_t needWs = aBytes + bBytes + (size_t)(N1 + N2) * sizeof(float);

    dim3 grid(N2 / TILE, N1 / TILE);      // 64 x 64 blocks

    if (ws_size >= needWs) {
        unsigned char* A16 = (unsigned char*)d_ws;
        unsigned char* B16 = A16 + aBytes;
        float* sq1 = (float*)(B16 + bBytes);
        float* sq2 = sq1 + N1;

        matern52_prep_kernel<<<dim3(N1 / 16), 256, 0, stream>>>(X1, l, A16, sq1, N1);
        matern52_prep_kernel<<<dim3(N2 / 16), 256, 0, stream>>>(X2, l, B16, sq2, N2);
        matern52_main_kernel<<<grid, 256, 0, stream>>>(A16, B16, sq1, sq2, c, out, N1, N2);
    } else {
        matern52_fallback_kernel<<<grid, 512, 0, stream>>>(X1, X2, c, l, out, N1, N2);
    }
}